// Round 4
// baseline (458.312 us; speedup 1.0000x reference)
//
#include <hip/hip_runtime.h>
#include <math.h>

// AttentionLayer: D=1024, N=50000, fp32.
// Algebra: exp(a_w.X[0]) cancels in (alpha@X)/sum(alpha) -> a_alpha unused.
// Per module: b_w = b_alpha@W_alpha; one pass over X accumulating
// num = sum_j exp(X[j].b_w) X[j], den = sum_j exp(X[j].b_w);
// res = (num/den)@W_sum; out = elu(concat(res_in,res_out) @ lin_W^T + lin_b).
//
// R3: stream X through wave-private LDS slots via global_load_lds (no dest
// VGPRs), counted vmcnt(4), zero barriers in main loop. FAILED: WAR race --
// stage(it+2) overwrites slot[it&1] (the slot read THIS iteration); issue
// order read<write is kept, but ds_read executes ~120cy after issue while
// the gl_lds LDS-write lands at data return (~200cy+): occasional overwrite
// before read -> absmax varied 5e-5..468 across runs.
// R4: s_waitcnt lgkmcnt(0) (+sched_barrier) before stage(it+2): LDS reads
// physically complete before the refill issues. ~120cy per ~1.5-2kcy
// iteration, hidden by 16 waves/CU.

#define DD 1024
#define NROWS 50000
#define GB 512     // blocks per module in attn_pass (grid 1024 = 4 blocks/CU)
#define NPART 16   // partial accumulation buffers per module

#define GLOAD_LDS16(g, l)                                    \
  __builtin_amdgcn_global_load_lds(                          \
      (const __attribute__((address_space(1))) void*)(g),    \
      (__attribute__((address_space(3))) void*)(l), 16, 0, 0)

// ---------------------------------------------------------------------------
// out[module*D+j] += sum_{i in chunk} v[i] * M[i*D+j]
// 256 blocks = 2 modules * 4 j-tiles * 32 i-chunks(32 rows). out pre-zeroed.
__global__ __launch_bounds__(256) void vecmat_partial(
    const float* __restrict__ v0, const float* __restrict__ M0,
    const float* __restrict__ v1, const float* __restrict__ M1,
    float* __restrict__ out) {
  int bid = blockIdx.x;
  int module = bid >> 7;          // 128 blocks per module
  int r = bid & 127;
  int jb = r & 3;                 // j tile (4 * 256 = 1024 columns)
  int ic = r >> 2;                // i chunk (32 * 32 = 1024 rows)
  const float* __restrict__ v = module ? v1 : v0;
  const float* __restrict__ M = module ? M1 : M0;
  int j = jb * 256 + threadIdx.x;
  int i0 = ic * 32;
  float acc = 0.f;
#pragma unroll 8
  for (int i = i0; i < i0 + 32; ++i)
    acc = fmaf(v[i], M[i * DD + j], acc);
  atomicAdd(&out[module * DD + j], acc);
}

// ---------------------------------------------------------------------------
// Main pass. Wave w owns rows {w, w+W, ...}. Per iteration: wait the row
// staged 2 iterations ago (vmcnt(4): 4 gl_lds per row, next row stays in
// flight), ds_read_b128 x4 -> dot with bwv -> wave64 butterfly -> exp ->
// fma into acc, lgkmcnt(0) (reads done), then stage row it+2 into the slot
// just freed. Slots are wave-private -> no barriers until the final combine.
__global__ __launch_bounds__(256) void attn_pass(
    const float* __restrict__ X0, const float* __restrict__ X1,
    const float* __restrict__ bw_all,
    float* __restrict__ num_part,   // [2][NPART][DD]
    float* __restrict__ den_part) { // [2][NPART]
  __shared__ float lds[4 * 2 * DD];   // [wave][slot][1024] = 32 KB
  __shared__ float dsum[4];

  int bid = blockIdx.x;
  int module = (bid >= GB) ? 1 : 0;
  int b = module ? bid - GB : bid;
  const float* __restrict__ X = module ? X1 : X0;
  const float* __restrict__ bw = bw_all + module * DD;

  int tid = threadIdx.x;
  int lane = tid & 63;
  int wave = tid >> 6;
  int w = b * 4 + wave;           // wave id within module
  const int W = GB * 4;           // waves per module = 2048

  float* __restrict__ slot = &lds[wave * 2 * DD];  // wave-private 2x1024

  float4 bwv[4], acc[4];
#pragma unroll
  for (int q = 0; q < 4; ++q) {
    bwv[q] = *reinterpret_cast<const float4*>(&bw[q * 256 + lane * 4]);
    acc[q] = make_float4(0.f, 0.f, 0.f, 0.f);
  }
  float asum = 0.f;

  int myrows = (NROWS - 1 - w) / W + 1;   // 24 or 25

  // stage row (w + it*W) into slot[it&1]; dummy row 0 past the end keeps
  // vmcnt arithmetic uniform (drained before LDS reuse).
  auto stage = [&](int it) {
    long row = (long)w + (long)it * W;
    const float* __restrict__ src = (row < NROWS) ? X + row * DD : X;
    float* dst = slot + (it & 1) * DD;
#pragma unroll
    for (int i = 0; i < 4; ++i)
      GLOAD_LDS16(src + i * 256 + lane * 4, dst + i * 256);
  };

  stage(0);
  stage(1);                       // 8 loads outstanding

  for (int it = 0; it < myrows; ++it) {
    asm volatile("s_waitcnt vmcnt(4)" ::: "memory");  // row `it` landed
    const float* __restrict__ s = slot + (it & 1) * DD;
    float4 xv[4];
#pragma unroll
    for (int q = 0; q < 4; ++q)
      xv[q] = *reinterpret_cast<const float4*>(&s[q * 256 + lane * 4]);
    // R4 race fix: the ds_reads above must have EXECUTED (not just issued)
    // before stage(it+2) can overwrite this slot. lgkmcnt(0) guarantees it;
    // memory clobber pins the reads above and the gl_lds below.
    asm volatile("s_waitcnt lgkmcnt(0)" ::: "memory");
    __builtin_amdgcn_sched_barrier(0);
    stage(it + 2);                // refill the slot just consumed (now safe)

    float t = 0.f;
#pragma unroll
    for (int q = 0; q < 4; ++q) {
      t = fmaf(xv[q].x, bwv[q].x, t);
      t = fmaf(xv[q].y, bwv[q].y, t);
      t = fmaf(xv[q].z, bwv[q].z, t);
      t = fmaf(xv[q].w, bwv[q].w, t);
    }
#pragma unroll
    for (int off = 32; off >= 1; off >>= 1) t += __shfl_xor(t, off, 64);
    float alpha = __expf(t);      // |t| ~ 0.05: native exp is exact enough
    asum += alpha;
#pragma unroll
    for (int q = 0; q < 4; ++q) {
      acc[q].x = fmaf(alpha, xv[q].x, acc[q].x);
      acc[q].y = fmaf(alpha, xv[q].y, acc[q].y);
      acc[q].z = fmaf(alpha, xv[q].z, acc[q].z);
      acc[q].w = fmaf(alpha, xv[q].w, acc[q].w);
    }
  }

  // Drain outstanding gl_lds (incl. dummies) before reusing LDS for combine.
  asm volatile("s_waitcnt vmcnt(0)" ::: "memory");
  __syncthreads();

  // block-level combine (4 waves): sdata aliases the stage buffers
  float* sdata = lds;             // [wave][1024] view, first 16 KB
#pragma unroll
  for (int q = 0; q < 4; ++q)
    *reinterpret_cast<float4*>(&sdata[wave * DD + q * 256 + lane * 4]) = acc[q];
  if (lane == 0) dsum[wave] = asum;  // asum identical across lanes of a wave
  __syncthreads();

  float4 a0 = *reinterpret_cast<float4*>(&sdata[0 * DD + tid * 4]);
  float4 a1 = *reinterpret_cast<float4*>(&sdata[1 * DD + tid * 4]);
  float4 a2 = *reinterpret_cast<float4*>(&sdata[2 * DD + tid * 4]);
  float4 a3 = *reinterpret_cast<float4*>(&sdata[3 * DD + tid * 4]);
  int p = module * NPART + (b & (NPART - 1));
  float* __restrict__ np = num_part + (size_t)p * DD;
  int c = tid * 4;
  atomicAdd(&np[c + 0], a0.x + a1.x + a2.x + a3.x);
  atomicAdd(&np[c + 1], a0.y + a1.y + a2.y + a3.y);
  atomicAdd(&np[c + 2], a0.z + a1.z + a2.z + a3.z);
  atomicAdd(&np[c + 3], a0.w + a1.w + a2.w + a3.w);
  if (tid == 0) atomicAdd(&den_part[p], dsum[0] + dsum[1] + dsum[2] + dsum[3]);
}

// ---------------------------------------------------------------------------
// num[m][i] = sum_p num_part[m][p][i]; den[m] = sum_p den_part[m][p]
__global__ __launch_bounds__(256) void reduce_partials(
    const float* __restrict__ num_part, const float* __restrict__ den_part,
    float* __restrict__ num, float* __restrict__ den) {
  int idx = blockIdx.x * 256 + threadIdx.x;   // grid 8*256 = 2048
  int m = idx >> 10;
  int i = idx & (DD - 1);
  float s = 0.f;
#pragma unroll
  for (int p = 0; p < NPART; ++p)
    s += num_part[((size_t)(m * NPART + p)) * DD + i];
  num[idx] = s;
  if (idx < 2) {
    float d = 0.f;
#pragma unroll
    for (int p = 0; p < NPART; ++p) d += den_part[idx * NPART + p];
    den[idx] = d;
  }
}

// ---------------------------------------------------------------------------
// out[k] = elu( sum_m res_raw[m]*inv_den(m) * lin_W[k*2048+m] + lin_b[k] )
__global__ __launch_bounds__(256) void final_kernel(
    const float* __restrict__ res_raw, const float* __restrict__ den,
    const float* __restrict__ linW, const float* __restrict__ linb,
    float* __restrict__ out) {
  int k = blockIdx.x;
  int tid = threadIdx.x;
  float inv0 = 1.f / den[0];
  float inv1 = 1.f / den[1];
  const float* __restrict__ row = linW + (size_t)k * (2 * DD);
  float acc = 0.f;
#pragma unroll
  for (int s = 0; s < 8; ++s) {
    int m = s * 256 + tid;
    float attn = res_raw[m] * (m < DD ? inv0 : inv1);
    acc = fmaf(attn, row[m], acc);
  }
#pragma unroll
  for (int off = 32; off >= 1; off >>= 1) acc += __shfl_xor(acc, off, 64);
  __shared__ float wsum[4];
  int lane = tid & 63, wave = tid >> 6;
  if (lane == 0) wsum[wave] = acc;
  __syncthreads();
  if (tid == 0) {
    float v = wsum[0] + wsum[1] + wsum[2] + wsum[3] + linb[k];
    out[k] = v > 0.f ? v : expm1f(v);
  }
}

// ---------------------------------------------------------------------------
extern "C" void kernel_launch(void* const* d_in, const int* in_sizes, int n_in,
                              void* d_out, int out_size, void* d_ws, size_t ws_size,
                              hipStream_t stream) {
  const float* X_in    = (const float*)d_in[0];
  const float* X_out   = (const float*)d_in[1];
  const float* W_a_in  = (const float*)d_in[2];
  // d_in[3] = a_alpha_in  (unused: exp(a_w.X[0]) cancels in normalization)
  const float* b_a_in  = (const float*)d_in[4];
  const float* W_s_in  = (const float*)d_in[5];
  const float* W_a_out = (const float*)d_in[6];
  // d_in[7] = a_alpha_out (unused)
  const float* b_a_out = (const float*)d_in[8];
  const float* W_s_out = (const float*)d_in[9];
  const float* linW    = (const float*)d_in[10];
  const float* linb    = (const float*)d_in[11];
  float* out = (float*)d_out;
  float* ws  = (float*)d_ws;

  // workspace layout (floats):
  float* bw       = ws;              // [2*1024]
  float* num_part = ws + 2048;       // [2*16*1024] = 32768
  float* den_part = ws + 34816;      // [32]
  float* num      = ws + 34848;      // [2048]
  float* den      = ws + 36896;      // [2]
  float* res_raw  = ws + 36898;      // [2048]
  // total 38946 floats ~ 152 KB

  hipMemsetAsync(d_ws, 0, 38946 * sizeof(float), stream);
  vecmat_partial<<<256, 256, 0, stream>>>(b_a_in, W_a_in, b_a_out, W_a_out, bw);
  attn_pass<<<2 * GB, 256, 0, stream>>>(X_in, X_out, bw, num_part, den_part);
  reduce_partials<<<8, 256, 0, stream>>>(num_part, den_part, num, den);
  vecmat_partial<<<256, 256, 0, stream>>>(num, W_s_in, num + 1024, W_s_out, res_raw);
  final_kernel<<<DD, 256, 0, stream>>>(res_raw, den, linW, linb, out);
}

// Round 6
// 451.204 us; speedup vs baseline: 1.0158x; 1.0158x over previous
//
#include <hip/hip_runtime.h>
#include <math.h>

// AttentionLayer: D=1024, N=50000, fp32.
// Algebra: exp(a_w.X[0]) cancels in (alpha@X)/sum(alpha) -> a_alpha unused.
// Per module: b_w = b_alpha@W_alpha; one pass over X accumulating
// num = sum_j exp(X[j].b_w) X[j], den = sum_j exp(X[j].b_w);
// res = (num/den)@W_sum; out = elu(concat(res_in,res_out) @ lin_W^T + lin_b).
//
// R0..R5 ledger: R0 (reg loads, RB=4, 16 waves/CU) = 137us attn. R2 (+2x grid,
// 32 waves offered) = flat. R4 (gl_lds dbuf, counted vmcnt, proven 2-row
// in-flight) = 150us. R5 (asm VGPR ring) = unsound (allocator may move asm
// output regs while load in flight) -> crashed. Delivered BW pinned at
// 3.0 TB/s across all three structures; occupancy/MLP/issue levers all flat.
// R6: revert to R0's exact attn_pass (best measured) + NPART 16->64 to cut
// the end-of-dispatch atomic slot contention 4x (1M atomics into 32 hot 4KB
// slots; R0->R2 marginal cost ~6us/1M suggests a ~6-12us tail).

#define DD 1024
#define NROWS 50000
#define GB 512     // blocks per module in attn_pass (grid 1024)
#define RB 4       // rows per wave iteration (50000 % 4 == 0 -> no tail)
#define NPART 64   // partial accumulation buffers per module (8 blocks/slot)

// ---------------------------------------------------------------------------
// out[module*D+j] += sum_{i in chunk} v[i] * M[i*D+j]
// 256 blocks = 2 modules * 4 j-tiles * 32 i-chunks(32 rows). out pre-zeroed.
__global__ __launch_bounds__(256) void vecmat_partial(
    const float* __restrict__ v0, const float* __restrict__ M0,
    const float* __restrict__ v1, const float* __restrict__ M1,
    float* __restrict__ out) {
  int bid = blockIdx.x;
  int module = bid >> 7;          // 128 blocks per module
  int r = bid & 127;
  int jb = r & 3;                 // j tile (4 * 256 = 1024 columns)
  int ic = r >> 2;                // i chunk (32 * 32 = 1024 rows)
  const float* __restrict__ v = module ? v1 : v0;
  const float* __restrict__ M = module ? M1 : M0;
  int j = jb * 256 + threadIdx.x;
  int i0 = ic * 32;
  float acc = 0.f;
#pragma unroll 8
  for (int i = i0; i < i0 + 32; ++i)
    acc = fmaf(v[i], M[i * DD + j], acc);
  atomicAdd(&out[module * DD + j], acc);
}

// ---------------------------------------------------------------------------
// Main pass: one wave handles RB rows per iteration. Lane l owns columns
// {q*256 + l*4 .. +3}, q<4. All 16 float4 loads issue before one vmcnt wait;
// the 4 butterfly-reduce chains are independent and pipeline.
__global__ __launch_bounds__(256, 4) void attn_pass(
    const float* __restrict__ X0, const float* __restrict__ X1,
    const float* __restrict__ bw_all,
    float* __restrict__ num_part,   // [2][NPART][DD]
    float* __restrict__ den_part) { // [2][NPART]
  int bid = blockIdx.x;
  int module = (bid >= GB) ? 1 : 0;
  int b = module ? bid - GB : bid;
  const float* __restrict__ X = module ? X1 : X0;
  const float* __restrict__ bw = bw_all + module * DD;

  int tid = threadIdx.x;
  int lane = tid & 63;
  int wave = tid >> 6;
  int w = b * 4 + wave;           // wave id within module
  const int WPM = GB * 4;         // waves per module

  float4 bwv[4], acc[4];
#pragma unroll
  for (int q = 0; q < 4; ++q) {
    bwv[q] = *reinterpret_cast<const float4*>(&bw[q * 256 + lane * 4]);
    acc[q] = make_float4(0.f, 0.f, 0.f, 0.f);
  }
  float asum = 0.f;

  for (int j0 = w * RB; j0 < NROWS; j0 += WPM * RB) {
    float4 xv[RB][4];
#pragma unroll
    for (int r = 0; r < RB; ++r) {
      const float4* __restrict__ row =
          reinterpret_cast<const float4*>(X + (size_t)(j0 + r) * DD);
#pragma unroll
      for (int q = 0; q < 4; ++q) xv[r][q] = row[q * 64 + lane];
    }
    float s[RB];
#pragma unroll
    for (int r = 0; r < RB; ++r) {
      float t = 0.f;
#pragma unroll
      for (int q = 0; q < 4; ++q) {
        t = fmaf(xv[r][q].x, bwv[q].x, t);
        t = fmaf(xv[r][q].y, bwv[q].y, t);
        t = fmaf(xv[r][q].z, bwv[q].z, t);
        t = fmaf(xv[r][q].w, bwv[q].w, t);
      }
      s[r] = t;
    }
    // 4 independent wave64 butterfly all-reduces (latency pipelines)
#pragma unroll
    for (int off = 32; off >= 1; off >>= 1) {
#pragma unroll
      for (int r = 0; r < RB; ++r) s[r] += __shfl_xor(s[r], off, 64);
    }
#pragma unroll
    for (int r = 0; r < RB; ++r) {
      float alpha = __expf(s[r]);   // |s| ~ 0.05: native exp is exact enough
      asum += alpha;
#pragma unroll
      for (int q = 0; q < 4; ++q) {
        acc[q].x = fmaf(alpha, xv[r][q].x, acc[q].x);
        acc[q].y = fmaf(alpha, xv[r][q].y, acc[q].y);
        acc[q].z = fmaf(alpha, xv[r][q].z, acc[q].z);
        acc[q].w = fmaf(alpha, xv[r][q].w, acc[q].w);
      }
    }
  }

  // block-level combine (4 waves) in LDS, then atomicAdd into 1-of-64 partials
  __shared__ float sdata[4][DD];
  __shared__ float dsum[4];
#pragma unroll
  for (int q = 0; q < 4; ++q)
    *reinterpret_cast<float4*>(&sdata[wave][q * 256 + lane * 4]) = acc[q];
  if (lane == 0) dsum[wave] = asum;  // asum identical across lanes of a wave
  __syncthreads();

  float4 a0 = *reinterpret_cast<float4*>(&sdata[0][tid * 4]);
  float4 a1 = *reinterpret_cast<float4*>(&sdata[1][tid * 4]);
  float4 a2 = *reinterpret_cast<float4*>(&sdata[2][tid * 4]);
  float4 a3 = *reinterpret_cast<float4*>(&sdata[3][tid * 4]);
  int p = module * NPART + (b & (NPART - 1));
  float* __restrict__ np = num_part + (size_t)p * DD;
  int c = tid * 4;
  atomicAdd(&np[c + 0], a0.x + a1.x + a2.x + a3.x);
  atomicAdd(&np[c + 1], a0.y + a1.y + a2.y + a3.y);
  atomicAdd(&np[c + 2], a0.z + a1.z + a2.z + a3.z);
  atomicAdd(&np[c + 3], a0.w + a1.w + a2.w + a3.w);
  if (tid == 0) atomicAdd(&den_part[p], dsum[0] + dsum[1] + dsum[2] + dsum[3]);
}

// ---------------------------------------------------------------------------
// num[m][i] = sum_p num_part[m][p][i]; den[m] = sum_p den_part[m][p]
__global__ __launch_bounds__(256) void reduce_partials(
    const float* __restrict__ num_part, const float* __restrict__ den_part,
    float* __restrict__ num, float* __restrict__ den) {
  int idx = blockIdx.x * 256 + threadIdx.x;   // grid 8*256 = 2048
  int m = idx >> 10;
  int i = idx & (DD - 1);
  float s = 0.f;
#pragma unroll 16
  for (int p = 0; p < NPART; ++p)
    s += num_part[((size_t)(m * NPART + p)) * DD + i];
  num[idx] = s;
  if (idx < 2) {
    float d = 0.f;
#pragma unroll 16
    for (int p = 0; p < NPART; ++p) d += den_part[idx * NPART + p];
    den[idx] = d;
  }
}

// ---------------------------------------------------------------------------
// out[k] = elu( sum_m res_raw[m]*inv_den(m) * lin_W[k*2048+m] + lin_b[k] )
__global__ __launch_bounds__(256) void final_kernel(
    const float* __restrict__ res_raw, const float* __restrict__ den,
    const float* __restrict__ linW, const float* __restrict__ linb,
    float* __restrict__ out) {
  int k = blockIdx.x;
  int tid = threadIdx.x;
  float inv0 = 1.f / den[0];
  float inv1 = 1.f / den[1];
  const float* __restrict__ row = linW + (size_t)k * (2 * DD);
  float acc = 0.f;
#pragma unroll
  for (int s = 0; s < 8; ++s) {
    int m = s * 256 + tid;
    float attn = res_raw[m] * (m < DD ? inv0 : inv1);
    acc = fmaf(attn, row[m], acc);
  }
#pragma unroll
  for (int off = 32; off >= 1; off >>= 1) acc += __shfl_xor(acc, off, 64);
  __shared__ float wsum[4];
  int lane = tid & 63, wave = tid >> 6;
  if (lane == 0) wsum[wave] = acc;
  __syncthreads();
  if (tid == 0) {
    float v = wsum[0] + wsum[1] + wsum[2] + wsum[3] + linb[k];
    out[k] = v > 0.f ? v : expm1f(v);
  }
}

// ---------------------------------------------------------------------------
extern "C" void kernel_launch(void* const* d_in, const int* in_sizes, int n_in,
                              void* d_out, int out_size, void* d_ws, size_t ws_size,
                              hipStream_t stream) {
  const float* X_in    = (const float*)d_in[0];
  const float* X_out   = (const float*)d_in[1];
  const float* W_a_in  = (const float*)d_in[2];
  // d_in[3] = a_alpha_in  (unused: exp(a_w.X[0]) cancels in normalization)
  const float* b_a_in  = (const float*)d_in[4];
  const float* W_s_in  = (const float*)d_in[5];
  const float* W_a_out = (const float*)d_in[6];
  // d_in[7] = a_alpha_out (unused)
  const float* b_a_out = (const float*)d_in[8];
  const float* W_s_out = (const float*)d_in[9];
  const float* linW    = (const float*)d_in[10];
  const float* linb    = (const float*)d_in[11];
  float* out = (float*)d_out;
  float* ws  = (float*)d_ws;

  // workspace layout (floats):
  float* bw       = ws;               // [2*1024]
  float* num_part = ws + 2048;        // [2*64*1024] = 131072
  float* den_part = ws + 133120;      // [128]
  float* num      = ws + 133248;      // [2048]
  float* den      = ws + 135296;      // [2]
  float* res_raw  = ws + 135298;      // [2048]
  // total 137346 floats ~ 537 KB

  hipMemsetAsync(d_ws, 0, 137346 * sizeof(float), stream);
  vecmat_partial<<<256, 256, 0, stream>>>(b_a_in, W_a_in, b_a_out, W_a_out, bw);
  attn_pass<<<2 * GB, 256, 0, stream>>>(X_in, X_out, bw, num_part, den_part);
  reduce_partials<<<8, 256, 0, stream>>>(num_part, den_part, num, den);
  vecmat_partial<<<256, 256, 0, stream>>>(num, W_s_in, num + 1024, W_s_out, res_raw);
  final_kernel<<<DD, 256, 0, stream>>>(res_raw, den, linW, linb, out);
}

// Round 7
// 447.881 us; speedup vs baseline: 1.0233x; 1.0074x over previous
//
#include <hip/hip_runtime.h>
#include <math.h>

// AttentionLayer: D=1024, N=50000, fp32.
// Algebra: exp(a_w.X[0]) cancels in (alpha@X)/sum(alpha) -> a_alpha unused.
// Per module: b_w = b_alpha@W_alpha; one pass over X accumulating
// num = sum_j exp(X[j].b_w) X[j], den = sum_j exp(X[j].b_w);
// res = (num/den)@W_sum; out = elu(concat(res_in,res_out) @ lin_W^T + lin_b).
//
// Ledger R0..R6: five attn_pass structures (reg-burst RB=4 / 2x grid /
// gl_lds dbuf / asm ring (unsound) / NPART), all levers flat, delivered BW
// pinned at 3.0 TB/s, all pipes <10%. R7 hypothesis: R0's VGPR=48 cannot
// hold xv[4][4] (64 regs) across its TWO uses (dot, then post-exp acc
// update) -> compiler RELOADS X rows from L2 for the acc pass. Invisible in
// counters (L2-hit, not VALU, not FETCH) but doubles real delivered BW to
// ~6 TB/s = m13 copy ceiling -> we were BW-saturated on phantom traffic.
// R7: RB=2 + ping-pong prefetch: cur+nxt = 64 buf VGPRs, total ~112 < 128
// cap at (256,4) -> xv provably register-resident, single-read by
// construction; prefetch also overlaps the reduce chain with next loads.

#define DD 1024
#define NROWS 50000
#define GB 512     // blocks per module in attn_pass (grid 1024, 16 waves/CU)
#define RB 2       // rows per wave iteration (ping-pong pair)
#define NPART 64   // partial accumulation buffers per module

// ---------------------------------------------------------------------------
// out[module*D+j] += sum_{i in chunk} v[i] * M[i*D+j]
// 256 blocks = 2 modules * 4 j-tiles * 32 i-chunks(32 rows). out pre-zeroed.
__global__ __launch_bounds__(256) void vecmat_partial(
    const float* __restrict__ v0, const float* __restrict__ M0,
    const float* __restrict__ v1, const float* __restrict__ M1,
    float* __restrict__ out) {
  int bid = blockIdx.x;
  int module = bid >> 7;          // 128 blocks per module
  int r = bid & 127;
  int jb = r & 3;                 // j tile (4 * 256 = 1024 columns)
  int ic = r >> 2;                // i chunk (32 * 32 = 1024 rows)
  const float* __restrict__ v = module ? v1 : v0;
  const float* __restrict__ M = module ? M1 : M0;
  int j = jb * 256 + threadIdx.x;
  int i0 = ic * 32;
  float acc = 0.f;
#pragma unroll 8
  for (int i = i0; i < i0 + 32; ++i)
    acc = fmaf(v[i], M[i * DD + j], acc);
  atomicAdd(&out[module * DD + j], acc);
}

// ---------------------------------------------------------------------------
// Main pass. Wave w owns row-pairs {w*2 + it*4096}. Per iteration: issue the
// NEXT pair's 8 float4 loads (independent, overlaps the chain below), then
// dot cur with bwv -> 2 pipelined wave64 butterflies -> exp -> acc fma
// (second use of cur, register-resident), then rename nxt->cur.
__global__ __launch_bounds__(256, 4) void attn_pass(
    const float* __restrict__ X0, const float* __restrict__ X1,
    const float* __restrict__ bw_all,
    float* __restrict__ num_part,   // [2][NPART][DD]
    float* __restrict__ den_part) { // [2][NPART]
  int bid = blockIdx.x;
  int module = (bid >= GB) ? 1 : 0;
  int b = module ? bid - GB : bid;
  const float* __restrict__ X = module ? X1 : X0;
  const float* __restrict__ bw = bw_all + module * DD;

  int tid = threadIdx.x;
  int lane = tid & 63;
  int wave = tid >> 6;
  int w = b * 4 + wave;           // wave id within module
  const int STRIDE = GB * 4 * RB; // 4096 rows per round

  float4 bwv[4], acc[4];
#pragma unroll
  for (int q = 0; q < 4; ++q) {
    bwv[q] = *reinterpret_cast<const float4*>(&bw[q * 256 + lane * 4]);
    acc[q] = make_float4(0.f, 0.f, 0.f, 0.f);
  }
  float asum = 0.f;

  float4 cur[RB][4], nxt[RB][4];
  int j0 = w * RB;                // always < NROWS (w < 2048)
#pragma unroll
  for (int r = 0; r < RB; ++r) {
    const float4* __restrict__ row =
        reinterpret_cast<const float4*>(X + (size_t)(j0 + r) * DD);
#pragma unroll
    for (int q = 0; q < 4; ++q) cur[r][q] = row[q * 64 + lane];
  }

  for (; j0 < NROWS; j0 += STRIDE) {
    int jn = j0 + STRIDE;
    bool have_next = jn < NROWS;  // wave-uniform
    if (have_next) {
#pragma unroll
      for (int r = 0; r < RB; ++r) {
        const float4* __restrict__ row =
            reinterpret_cast<const float4*>(X + (size_t)(jn + r) * DD);
#pragma unroll
        for (int q = 0; q < 4; ++q) nxt[r][q] = row[q * 64 + lane];
      }
    }

    float s[RB];
#pragma unroll
    for (int r = 0; r < RB; ++r) {
      float t = 0.f;
#pragma unroll
      for (int q = 0; q < 4; ++q) {
        t = fmaf(cur[r][q].x, bwv[q].x, t);
        t = fmaf(cur[r][q].y, bwv[q].y, t);
        t = fmaf(cur[r][q].z, bwv[q].z, t);
        t = fmaf(cur[r][q].w, bwv[q].w, t);
      }
      s[r] = t;
    }
    // 2 independent wave64 butterfly all-reduces (latency pipelines)
#pragma unroll
    for (int off = 32; off >= 1; off >>= 1) {
#pragma unroll
      for (int r = 0; r < RB; ++r) s[r] += __shfl_xor(s[r], off, 64);
    }
#pragma unroll
    for (int r = 0; r < RB; ++r) {
      float alpha = __expf(s[r]);   // |s| ~ 0.05: native exp is exact enough
      asum += alpha;
#pragma unroll
      for (int q = 0; q < 4; ++q) {
        acc[q].x = fmaf(alpha, cur[r][q].x, acc[q].x);
        acc[q].y = fmaf(alpha, cur[r][q].y, acc[q].y);
        acc[q].z = fmaf(alpha, cur[r][q].z, acc[q].z);
        acc[q].w = fmaf(alpha, cur[r][q].w, acc[q].w);
      }
    }
    if (have_next) {
#pragma unroll
      for (int r = 0; r < RB; ++r)
#pragma unroll
        for (int q = 0; q < 4; ++q) cur[r][q] = nxt[r][q];
    }
  }

  // block-level combine (4 waves) in LDS, then atomicAdd into 1-of-64 partials
  __shared__ float sdata[4][DD];
  __shared__ float dsum[4];
#pragma unroll
  for (int q = 0; q < 4; ++q)
    *reinterpret_cast<float4*>(&sdata[wave][q * 256 + lane * 4]) = acc[q];
  if (lane == 0) dsum[wave] = asum;  // asum identical across lanes of a wave
  __syncthreads();

  float4 a0 = *reinterpret_cast<float4*>(&sdata[0][tid * 4]);
  float4 a1 = *reinterpret_cast<float4*>(&sdata[1][tid * 4]);
  float4 a2 = *reinterpret_cast<float4*>(&sdata[2][tid * 4]);
  float4 a3 = *reinterpret_cast<float4*>(&sdata[3][tid * 4]);
  int p = module * NPART + (b & (NPART - 1));
  float* __restrict__ np = num_part + (size_t)p * DD;
  int c = tid * 4;
  atomicAdd(&np[c + 0], a0.x + a1.x + a2.x + a3.x);
  atomicAdd(&np[c + 1], a0.y + a1.y + a2.y + a3.y);
  atomicAdd(&np[c + 2], a0.z + a1.z + a2.z + a3.z);
  atomicAdd(&np[c + 3], a0.w + a1.w + a2.w + a3.w);
  if (tid == 0) atomicAdd(&den_part[p], dsum[0] + dsum[1] + dsum[2] + dsum[3]);
}

// ---------------------------------------------------------------------------
// num[m][i] = sum_p num_part[m][p][i]; den[m] = sum_p den_part[m][p]
__global__ __launch_bounds__(256) void reduce_partials(
    const float* __restrict__ num_part, const float* __restrict__ den_part,
    float* __restrict__ num, float* __restrict__ den) {
  int idx = blockIdx.x * 256 + threadIdx.x;   // grid 8*256 = 2048
  int m = idx >> 10;
  int i = idx & (DD - 1);
  float s = 0.f;
#pragma unroll 16
  for (int p = 0; p < NPART; ++p)
    s += num_part[((size_t)(m * NPART + p)) * DD + i];
  num[idx] = s;
  if (idx < 2) {
    float d = 0.f;
#pragma unroll 16
    for (int p = 0; p < NPART; ++p) d += den_part[idx * NPART + p];
    den[idx] = d;
  }
}

// ---------------------------------------------------------------------------
// out[k] = elu( sum_m res_raw[m]*inv_den(m) * lin_W[k*2048+m] + lin_b[k] )
__global__ __launch_bounds__(256) void final_kernel(
    const float* __restrict__ res_raw, const float* __restrict__ den,
    const float* __restrict__ linW, const float* __restrict__ linb,
    float* __restrict__ out) {
  int k = blockIdx.x;
  int tid = threadIdx.x;
  float inv0 = 1.f / den[0];
  float inv1 = 1.f / den[1];
  const float* __restrict__ row = linW + (size_t)k * (2 * DD);
  float acc = 0.f;
#pragma unroll
  for (int s = 0; s < 8; ++s) {
    int m = s * 256 + tid;
    float attn = res_raw[m] * (m < DD ? inv0 : inv1);
    acc = fmaf(attn, row[m], acc);
  }
#pragma unroll
  for (int off = 32; off >= 1; off >>= 1) acc += __shfl_xor(acc, off, 64);
  __shared__ float wsum[4];
  int lane = tid & 63, wave = tid >> 6;
  if (lane == 0) wsum[wave] = acc;
  __syncthreads();
  if (tid == 0) {
    float v = wsum[0] + wsum[1] + wsum[2] + wsum[3] + linb[k];
    out[k] = v > 0.f ? v : expm1f(v);
  }
}

// ---------------------------------------------------------------------------
extern "C" void kernel_launch(void* const* d_in, const int* in_sizes, int n_in,
                              void* d_out, int out_size, void* d_ws, size_t ws_size,
                              hipStream_t stream) {
  const float* X_in    = (const float*)d_in[0];
  const float* X_out   = (const float*)d_in[1];
  const float* W_a_in  = (const float*)d_in[2];
  // d_in[3] = a_alpha_in  (unused: exp(a_w.X[0]) cancels in normalization)
  const float* b_a_in  = (const float*)d_in[4];
  const float* W_s_in  = (const float*)d_in[5];
  const float* W_a_out = (const float*)d_in[6];
  // d_in[7] = a_alpha_out (unused)
  const float* b_a_out = (const float*)d_in[8];
  const float* W_s_out = (const float*)d_in[9];
  const float* linW    = (const float*)d_in[10];
  const float* linb    = (const float*)d_in[11];
  float* out = (float*)d_out;
  float* ws  = (float*)d_ws;

  // workspace layout (floats):
  float* bw       = ws;               // [2*1024]
  float* num_part = ws + 2048;        // [2*64*1024] = 131072
  float* den_part = ws + 133120;      // [128]
  float* num      = ws + 133248;      // [2048]
  float* den      = ws + 135296;      // [2]
  float* res_raw  = ws + 135298;      // [2048]
  // total 137346 floats ~ 537 KB

  hipMemsetAsync(d_ws, 0, 137346 * sizeof(float), stream);
  vecmat_partial<<<256, 256, 0, stream>>>(b_a_in, W_a_in, b_a_out, W_a_out, bw);
  attn_pass<<<2 * GB, 256, 0, stream>>>(X_in, X_out, bw, num_part, den_part);
  reduce_partials<<<8, 256, 0, stream>>>(num_part, den_part, num, den);
  vecmat_partial<<<256, 256, 0, stream>>>(num, W_s_in, num + 1024, W_s_out, res_raw);
  final_kernel<<<DD, 256, 0, stream>>>(res_raw, den, linW, linb, out);
}